// Round 7
// baseline (10555.144 us; speedup 1.0000x reference)
//
#include <hip/hip_runtime.h>
#include <stdint.h>

#define NN    200000   // nodes
#define NE    100000   // edges
#define HD    128      // hidden/memory/time dim
#define EFD   64       // edge feat dim
#define NG    384      // 3*HD gates

typedef unsigned long long u64;

// ---- ws layout (bytes) ----
#define OFF_KEY   ((size_t)0)            // u64 * NN = 1,600,000
#define OFF_CNT   ((size_t)1600000)      // int
#define OFF_LIST  ((size_t)1600256)      // int * NN = 800,000
#define OFF_UV    ((size_t)2400256)      // float * NN*128 = 102,400,000
#define OFF_HN    ((size_t)104800256)    // float * NE*32 = 12,800,000
#define OFF_A     ((size_t)117600256)    // float * 2048
#define OFF_B     ((size_t)117608448)    // float * 2048
#define OFF_C0    ((size_t)117616640)    // float * 64 (+pad)
#define WS_NEED   ((size_t)117616896)

__device__ __forceinline__ float frcp(float x){ return __builtin_amdgcn_rcpf(x); }
__device__ __forceinline__ float sigf(float x){ return frcp(1.f + __expf(-x)); }
__device__ __forceinline__ float tanhf_(float x){ return 1.f - 2.f*frcp(__expf(2.f*x) + 1.f); }
__device__ __forceinline__ float4 ld4(const float* p){ return *reinterpret_cast<const float4*>(p); }

// async global->LDS, 16B per lane; LDS dest = (first lane's ptr) + lane*16.
__device__ __forceinline__ void gl16(const float* g, float* l) {
  __builtin_amdgcn_global_load_lds(
      (const __attribute__((address_space(1))) void*)g,
      (__attribute__((address_space(3))) void*)l, 16, 0, 0);
}

// ---------- per-node winner key: max (t, isDst, e) ----------
__global__ void k_scatter(const int* __restrict__ src, const int* __restrict__ dst,
                          const int* __restrict__ t, u64* __restrict__ key) {
  int e = blockIdx.x*256 + threadIdx.x;
  if (e >= NE) return;
  u64 tt = (u64)(unsigned)(t[e] + 1);
  atomicMax(&key[src[e]], (tt<<18) | (u64)(unsigned)e);
  atomicMax(&key[dst[e]], (tt<<18) | (1ULL<<17) | (u64)(unsigned)e);
}

__global__ void k_compact(const u64* __restrict__ key, int* __restrict__ list,
                          int* __restrict__ count) {
  int n = blockIdx.x*256 + threadIdx.x;
  if (n >= NN) return;
  if (key[n] != 0ULL) { int p = atomicAdd(count, 1); list[p] = n; }
}

// ---------- fold W1/W_sp/W_pp/biases: A=W1a@W_sp, B=(W1b+W1c)@W_pp, c0 ----------
__global__ void k_pre(const float* __restrict__ W1, const float* __restrict__ W_sp,
                      const float* __restrict__ W_pp, const float* __restrict__ b_sp,
                      const float* __restrict__ b_pp, const float* __restrict__ b1,
                      float* __restrict__ A, float* __restrict__ B, float* __restrict__ c0)
{
  int tid = blockIdx.x*256 + threadIdx.x;
  if (tid < 2048) {
    int o = tid >> 5, j = tid & 31;
    float s = 0.f;
    for (int k = 0; k < 128; ++k) s = fmaf(W1[o*NG + k], W_sp[k*32 + j], s);
    A[tid] = s;
  } else if (tid < 4096) {
    int q = tid - 2048;
    int o = q >> 5, j = q & 31;
    float s = 0.f;
    for (int k = 0; k < 128; ++k)
      s = fmaf(W1[o*NG + 128 + k] + W1[o*NG + 256 + k], W_pp[k*32 + j], s);
    B[q] = s;
  } else if (tid < 4160) {
    int o = tid - 4096;
    float s = b1[o];
    for (int k = 0; k < 128; ++k) {
      s = fmaf(W1[o*NG + k], b_sp[k], s);
      s = fmaf(W1[o*NG + 128 + k] + W1[o*NG + 256 + k], b_pp[k], s);
    }
    c0[o] = s;
  }
}

// ---------- GRU: 64 nodes/block, 256 thr, 8 nodes/thread, 256-VGPR budget ----------
// Round-4 structure (acc[8][12]+accN[8][4]) + global_load_lds W staging (zero data
// regs, source pre-swizzled so linear lane->LDS lands in the XOR-swizzled slot).
// launch_bounds(256,2): 8 waves/CU -> 2 waves/SIMD -> 256 VGPR cap (no spill).
__global__ __launch_bounds__(256, 2) void k_gru(
    const u64* __restrict__ key, const int* __restrict__ list, const int* __restrict__ count,
    const int* __restrict__ src, const int* __restrict__ dst, const int* __restrict__ t,
    const float* __restrict__ msg, const float* __restrict__ memory,
    const float* __restrict__ last_update,
    const float* __restrict__ w_t, const float* __restrict__ b_t,
    const float* __restrict__ W_ih, const float* __restrict__ b_ih,
    const float* __restrict__ W_hh, const float* __restrict__ b_hh,
    const float* __restrict__ W1, float* __restrict__ uv)
{
  __shared__ float Ws[12288];          // [384 g][32 k], XOR-swizzled quads (48KB)
  __shared__ float Xs[2048];           // [64 node][32 k] chunk (8KB)
  __shared__ int   sn_self[64];
  __shared__ int   sn_other[64];
  __shared__ int   sn_e[64];
  __shared__ float sn_dt[64];

  int cnt = count[0];
  int base = blockIdx.x * 64;
  if (base >= cnt) return;
  int tid = threadIdx.x;
  int tx = tid & 31, ty = tid >> 5;    // ty 0..7

  if (tid < 64) {
    int idx = base + tid;
    int cl = idx < cnt ? idx : (cnt - 1);
    int n = list[cl];
    u64 k = key[n];
    int e   = (int)(k & 0x1FFFFULL);
    int isd = (int)((k >> 17) & 1ULL);
    sn_self[tid]  = n;
    sn_other[tid] = isd ? src[e] : dst[e];
    sn_e[tid]     = e;
    sn_dt[tid]    = (float)t[e] - last_update[n];
  }
  __syncthreads();

  float acc[8][12];
  float accN[8][4];
  #pragma unroll
  for (int a=0;a<8;++a){
    #pragma unroll
    for (int b=0;b<12;++b) acc[a][b]=0.f;
    #pragma unroll
    for (int b=0;b<4;++b) accN[a][b]=0.f;
  }

  for (int ch = 0; ch < 18; ++ch) {
    // W chunk: 3072 quads via global_load_lds (12 calls x 256 lanes).
    // LDS slot q holds data for (g=q>>3, k4=(q&7)^(g&7)) -> read-side swizzle matches.
    #pragma unroll
    for (int i = 0; i < 12; ++i) {
      int q = i*256 + tid;
      int g = q >> 3;
      int k4 = (q & 7) ^ (g & 7);
      int k = ch*32 + k4*4;
      const float* srcp = (k < 448) ? (W_ih + (size_t)g*448 + k)
                                    : (W_hh + (size_t)g*HD + (k-448));
      gl16(srcp, &Ws[q*4]);
    }
    // X chunk: 64 nodes x 32 k = 512 float4, 2 per thread (regs, has cos compute)
    #pragma unroll
    for (int i = 0; i < 2; ++i) {
      int idx = tid + 256*i;
      int nodeL = idx >> 3, k4 = idx & 7;
      int k = ch*32 + k4*4;
      int self = sn_self[nodeL], other = sn_other[nodeL], e = sn_e[nodeL];
      float4 vx;
      if (k < 128)      vx = ld4(memory + (size_t)self*HD + k);
      else if (k < 256) vx = ld4(memory + (size_t)other*HD + (k-128));
      else if (k < 320) vx = ld4(msg + (size_t)e*EFD + (k-256));
      else if (k < 448) {
        int kk = k - 320; float dt = sn_dt[nodeL];
        vx.x = cosf(fmaf(dt, w_t[kk],   b_t[kk]));
        vx.y = cosf(fmaf(dt, w_t[kk+1], b_t[kk+1]));
        vx.z = cosf(fmaf(dt, w_t[kk+2], b_t[kk+2]));
        vx.w = cosf(fmaf(dt, w_t[kk+3], b_t[kk+3]));
      } else            vx = ld4(memory + (size_t)self*HD + (k-448));
      *reinterpret_cast<float4*>(&Xs[nodeL*32 + k4*4]) = vx;
    }
    __syncthreads();   // drains vmcnt (global_load_lds) + lgkm

    bool memPart = (ch >= 14);
    #pragma unroll
    for (int k4 = 0; k4 < 8; ++k4) {
      float4 xv[8];
      #pragma unroll
      for (int nn = 0; nn < 8; ++nn)
        xv[nn] = *reinterpret_cast<const float4*>(&Xs[(ty + 8*nn)*32 + k4*4]);
      #pragma unroll
      for (int gg = 0; gg < 12; ++gg) {
        int g = tx + 32*gg;
        float4 w = *reinterpret_cast<const float4*>(&Ws[g*32 + ((k4 ^ (g&7))<<2)]);
        if (gg < 8) {
          #pragma unroll
          for (int nn = 0; nn < 8; ++nn) {
            acc[nn][gg] = fmaf(w.x, xv[nn].x, acc[nn][gg]);
            acc[nn][gg] = fmaf(w.y, xv[nn].y, acc[nn][gg]);
            acc[nn][gg] = fmaf(w.z, xv[nn].z, acc[nn][gg]);
            acc[nn][gg] = fmaf(w.w, xv[nn].w, acc[nn][gg]);
          }
        } else if (!memPart) {
          #pragma unroll
          for (int nn = 0; nn < 8; ++nn) {
            acc[nn][gg] = fmaf(w.x, xv[nn].x, acc[nn][gg]);
            acc[nn][gg] = fmaf(w.y, xv[nn].y, acc[nn][gg]);
            acc[nn][gg] = fmaf(w.z, xv[nn].z, acc[nn][gg]);
            acc[nn][gg] = fmaf(w.w, xv[nn].w, acc[nn][gg]);
          }
        } else {
          #pragma unroll
          for (int nn = 0; nn < 8; ++nn) {
            accN[nn][gg-8] = fmaf(w.x, xv[nn].x, accN[nn][gg-8]);
            accN[nn][gg-8] = fmaf(w.y, xv[nn].y, accN[nn][gg-8]);
            accN[nn][gg-8] = fmaf(w.z, xv[nn].z, accN[nn][gg-8]);
            accN[nn][gg-8] = fmaf(w.w, xv[nn].w, accN[nn][gg-8]);
          }
        }
      }
    }
    __syncthreads();
  }

  // epilogue: GRU gates -> mem_new tile in LDS (overlay Ws[4096..12288))
  float* Mn = &Ws[4096];   // [64][128]
  #pragma unroll
  for (int nn = 0; nn < 8; ++nn) {
    int nl = ty + 8*nn;
    int self = sn_self[nl];
    #pragma unroll
    for (int hh = 0; hh < 4; ++hh) {
      int h = tx + 32*hh;
      float r  = sigf(acc[nn][hh]     + b_ih[h]       + b_hh[h]);
      float z  = sigf(acc[nn][4+hh]   + b_ih[128+h]   + b_hh[128+h]);
      float nv = tanhf_(acc[nn][8+hh] + b_ih[256+h] + r*(accN[nn][hh] + b_hh[256+h]));
      float m  = memory[(size_t)self*HD + h];
      Mn[nl*128 + h] = (1.f - z)*nv + z*m;
    }
  }
  __syncthreads();

  // uv = [W1a@mn | W1b@mn] : K=128 chunked by 32, W1 chunk staged at Ws[0..4096)
  float acc2[8][4];
  #pragma unroll
  for (int a=0;a<8;++a){
    #pragma unroll
    for (int b=0;b<4;++b) acc2[a][b]=0.f;
  }
  for (int ch = 0; ch < 4; ++ch) {
    #pragma unroll
    for (int i = 0; i < 4; ++i) {
      int idx = tid + 256*i;
      int o = idx >> 3, k4 = idx & 7;
      int k = ch*32 + k4*4;
      float4 w = (o < 64) ? ld4(W1 + (size_t)o*NG + k)
                          : ld4(W1 + (size_t)(o-64)*NG + 128 + k);
      *reinterpret_cast<float4*>(&Ws[o*32 + ((k4 ^ (o&7))<<2)]) = w;
    }
    __syncthreads();
    #pragma unroll
    for (int k4 = 0; k4 < 8; ++k4) {
      float4 xv[8];
      #pragma unroll
      for (int nn = 0; nn < 8; ++nn)
        xv[nn] = *reinterpret_cast<const float4*>(&Mn[(ty+8*nn)*128 + ch*32 + k4*4]);
      #pragma unroll
      for (int og = 0; og < 4; ++og) {
        int o = tx + 32*og;
        float4 w = *reinterpret_cast<const float4*>(&Ws[o*32 + ((k4 ^ (o&7))<<2)]);
        #pragma unroll
        for (int nn = 0; nn < 8; ++nn) {
          acc2[nn][og] = fmaf(w.x, xv[nn].x, acc2[nn][og]);
          acc2[nn][og] = fmaf(w.y, xv[nn].y, acc2[nn][og]);
          acc2[nn][og] = fmaf(w.z, xv[nn].z, acc2[nn][og]);
          acc2[nn][og] = fmaf(w.w, xv[nn].w, acc2[nn][og]);
        }
      }
    }
    __syncthreads();
  }
  #pragma unroll
  for (int nn = 0; nn < 8; ++nn) {
    int nl = ty + 8*nn;
    if (base + nl < cnt) {
      int self = sn_self[nl];
      #pragma unroll
      for (int og = 0; og < 4; ++og)
        uv[(size_t)self*128 + tx + 32*og] = acc2[nn][og];
    }
  }
}

// ---------- price LSTM: thread (g,j) owns hidden unit j of edge g ----------
__global__ __launch_bounds__(256) void k_lstm(
    const float* __restrict__ price, const float* __restrict__ W_ihl,
    const float* __restrict__ W_hhl, const float* __restrict__ b_ihl,
    const float* __restrict__ b_hhl, float* __restrict__ hn_out)
{
  __shared__ float Wsh[4096];     // W_hh row-major [128][32] = 16KB
  __shared__ float ps[8][52];     // price rows (pad to 52)
  __shared__ float hrow[8][36];   // h per edge (stride 36)
  int tid = threadIdx.x;
  int g = tid >> 5;               // edge slot 0..7
  int j = tid & 31;               // hidden unit

  for (int i = tid; i < 1024; i += 256)
    *reinterpret_cast<float4*>(&Wsh[i*4]) = ld4(W_hhl + i*4);
  {
    int ebase = blockIdx.x*8;
    int m = NE - ebase; if (m > 8) m = 8;
    const float* pb = price + (size_t)ebase*50;
    for (int i = tid; i < m*50; i += 256) ps[i/50][i%50] = pb[i];
  }
  __syncthreads();

  float wi[32], wf[32], wg[32], wo[32];
  #pragma unroll
  for (int k = 0; k < 32; ++k) {
    wi[k] = Wsh[j*32 + k];
    wf[k] = Wsh[(32+j)*32 + k];
    wg[k] = Wsh[(64+j)*32 + k];
    wo[k] = Wsh[(96+j)*32 + k];
  }
  float wxi = W_ihl[j],    wxf = W_ihl[32+j], wxg = W_ihl[64+j], wxo = W_ihl[96+j];
  float bi  = b_ihl[j]    + b_hhl[j];
  float bf  = b_ihl[32+j] + b_hhl[32+j];
  float bg  = b_ihl[64+j] + b_hhl[64+j];
  float bo  = b_ihl[96+j] + b_hhl[96+j];

  float c = 0.f, hlast = 0.f;
  hrow[g][j] = 0.f;
  __syncthreads();

  #pragma unroll 1
  for (int s = 0; s < 50; ++s) {
    float x = ps[g][s];
    float ai = fmaf(x, wxi, bi);
    float af = fmaf(x, wxf, bf);
    float ag = fmaf(x, wxg, bg);
    float ao = fmaf(x, wxo, bo);
    #pragma unroll
    for (int k4 = 0; k4 < 8; ++k4) {
      float4 hv = *reinterpret_cast<const float4*>(&hrow[g][k4*4]);
      int b = k4*4;
      ai = fmaf(wi[b],hv.x, fmaf(wi[b+1],hv.y, fmaf(wi[b+2],hv.z, fmaf(wi[b+3],hv.w, ai))));
      af = fmaf(wf[b],hv.x, fmaf(wf[b+1],hv.y, fmaf(wf[b+2],hv.z, fmaf(wf[b+3],hv.w, af))));
      ag = fmaf(wg[b],hv.x, fmaf(wg[b+1],hv.y, fmaf(wg[b+2],hv.z, fmaf(wg[b+3],hv.w, ag))));
      ao = fmaf(wo[b],hv.x, fmaf(wo[b+1],hv.y, fmaf(wo[b+2],hv.z, fmaf(wo[b+3],hv.w, ao))));
    }
    float ig = sigf(ai), fg = sigf(af), gv = tanhf_(ag), og = sigf(ao);
    c = fmaf(fg, c, ig*gv);
    hlast = og * tanhf_(c);
    hrow[g][j] = hlast;
  }

  int e = blockIdx.x*8 + g;
  if (e < NE) hn_out[(size_t)e*32 + j] = hlast;
}

// ---------- fused output: out = W2 @ relu(u[s] + v[d] + A@sf + B@hn + c0) + b2 ----------
__global__ __launch_bounds__(256) void k_final(
    const int* __restrict__ src, const int* __restrict__ dst, const int* __restrict__ xst,
    const float* __restrict__ party, const float* __restrict__ state,
    const float* __restrict__ uv, const float* __restrict__ hn,
    const float* __restrict__ A, const float* __restrict__ B, const float* __restrict__ c0,
    const float* __restrict__ W2, const float* __restrict__ b2, float* __restrict__ out)
{
  __shared__ float As[2048], Bs[2048], c0s[64], W2s[64];
  int tid = threadIdx.x;
  for (int i = tid; i < 2048; i += 256) { As[i] = A[i]; Bs[i] = B[i]; }
  if (tid < 64) { c0s[tid] = c0[tid]; W2s[tid] = W2[tid]; }
  __syncthreads();
  int e = blockIdx.x*256 + tid;
  if (e >= NE) return;
  int s = src[e], d = dst[e];
  int p = xst[2*s], stt = xst[2*s + 1];
  float4 sf4[8], hv4[8];
  #pragma unroll
  for (int i = 0; i < 4; ++i) sf4[i]   = ld4(party + p*16 + i*4);
  #pragma unroll
  for (int i = 0; i < 4; ++i) sf4[4+i] = ld4(state + stt*16 + i*4);
  #pragma unroll
  for (int i = 0; i < 8; ++i) hv4[i] = ld4(hn + (size_t)e*32 + i*4);
  const float* urow = uv + (size_t)s*128;
  const float* vrow = uv + (size_t)d*128 + 64;
  float oacc = b2[0];
  #pragma unroll 4
  for (int o4 = 0; o4 < 16; ++o4) {
    float4 u4 = ld4(urow + o4*4);
    float4 v4 = ld4(vrow + o4*4);
    float4 cc = *reinterpret_cast<const float4*>(&c0s[o4*4]);
    float4 w2 = *reinterpret_cast<const float4*>(&W2s[o4*4]);
    float hh[4] = {u4.x+v4.x+cc.x, u4.y+v4.y+cc.y, u4.z+v4.z+cc.z, u4.w+v4.w+cc.w};
    #pragma unroll
    for (int oo = 0; oo < 4; ++oo) {
      int o = o4*4 + oo;
      float acc = hh[oo];
      #pragma unroll
      for (int j4 = 0; j4 < 8; ++j4) {
        float4 a = *reinterpret_cast<const float4*>(&As[o*32 + j4*4]);
        float4 b = *reinterpret_cast<const float4*>(&Bs[o*32 + j4*4]);
        float4 sfv = sf4[j4], hvv = hv4[j4];
        acc = fmaf(a.x,sfv.x, fmaf(a.y,sfv.y, fmaf(a.z,sfv.z, fmaf(a.w,sfv.w, acc))));
        acc = fmaf(b.x,hvv.x, fmaf(b.y,hvv.y, fmaf(b.z,hvv.z, fmaf(b.w,hvv.w, acc))));
      }
      float w2v = (oo==0) ? w2.x : (oo==1) ? w2.y : (oo==2) ? w2.z : w2.w;
      oacc = fmaf(w2v, fmaxf(acc, 0.f), oacc);
    }
  }
  out[e] = oacc;
}

extern "C" void kernel_launch(void* const* d_in, const int* in_sizes, int n_in,
                              void* d_out, int out_size, void* d_ws, size_t ws_size,
                              hipStream_t stream) {
  const int*   src   = (const int*)d_in[0];
  const int*   dst   = (const int*)d_in[1];
  const int*   t     = (const int*)d_in[2];
  const float* msg   = (const float*)d_in[3];
  const float* price = (const float*)d_in[4];
  // d_in[5] trade_t: unused by reference
  const int*   xst   = (const int*)d_in[6];
  const float* memory= (const float*)d_in[7];
  const float* lu    = (const float*)d_in[8];
  const float* w_t   = (const float*)d_in[9];
  const float* b_t   = (const float*)d_in[10];
  const float* W_ih  = (const float*)d_in[11];
  const float* b_ih  = (const float*)d_in[12];
  const float* W_hh  = (const float*)d_in[13];
  const float* b_hh  = (const float*)d_in[14];
  const float* party = (const float*)d_in[15];
  const float* state = (const float*)d_in[16];
  const float* W_sp  = (const float*)d_in[17];
  const float* b_sp  = (const float*)d_in[18];
  const float* W_ihl = (const float*)d_in[19];
  const float* W_hhl = (const float*)d_in[20];
  const float* b_ihl = (const float*)d_in[21];
  const float* b_hhl = (const float*)d_in[22];
  const float* W_pp  = (const float*)d_in[23];
  const float* b_pp  = (const float*)d_in[24];
  const float* W1    = (const float*)d_in[25];
  const float* b1    = (const float*)d_in[26];
  const float* W2    = (const float*)d_in[27];
  const float* b2    = (const float*)d_in[28];
  float* out = (float*)d_out;

  if (ws_size < WS_NEED) {              // loud failure: zero output
    (void)hipMemsetAsync(d_out, 0, (size_t)out_size*4, stream);
    return;
  }

  char* ws = (char*)d_ws;
  u64*   key  = (u64*)(ws + OFF_KEY);
  int*   cnt  = (int*)(ws + OFF_CNT);
  int*   list = (int*)(ws + OFF_LIST);
  float* uv   = (float*)(ws + OFF_UV);
  float* hn   = (float*)(ws + OFF_HN);
  float* A    = (float*)(ws + OFF_A);
  float* B    = (float*)(ws + OFF_B);
  float* c0   = (float*)(ws + OFF_C0);

  (void)hipMemsetAsync(ws, 0, OFF_LIST, stream);   // zero key[] + count
  k_scatter<<<(NE+255)/256, 256, 0, stream>>>(src, dst, t, key);
  k_compact<<<(NN+255)/256, 256, 0, stream>>>(key, list, cnt);
  k_pre<<<17, 256, 0, stream>>>(W1, W_sp, W_pp, b_sp, b_pp, b1, A, B, c0);
  k_lstm<<<(NE+7)/8, 256, 0, stream>>>(price, W_ihl, W_hhl, b_ihl, b_hhl, hn);
  k_gru<<<(NN+63)/64, 256, 0, stream>>>(key, list, cnt, src, dst, t, msg, memory, lu,
                                        w_t, b_t, W_ih, b_ih, W_hh, b_hh, W1, uv);
  k_final<<<(NE+255)/256, 256, 0, stream>>>(src, dst, xst, party, state, uv, hn,
                                            A, B, c0, W2, b2, out);
}

// Round 8
// 7453.629 us; speedup vs baseline: 1.4161x; 1.4161x over previous
//
#include <hip/hip_runtime.h>
#include <stdint.h>

#define NN    200000   // nodes
#define NE    100000   // edges
#define HD    128      // hidden/memory/time dim
#define EFD   64       // edge feat dim
#define NG    384      // 3*HD gates

typedef unsigned long long u64;

// ---- ws layout (bytes) ----
#define OFF_KEY   ((size_t)0)            // u64 * NN = 1,600,000
#define OFF_CNT   ((size_t)1600000)      // int
#define OFF_LIST  ((size_t)1600256)      // int * NN = 800,000
#define OFF_UV    ((size_t)2400256)      // float * NN*128 = 102,400,000
#define OFF_HN    ((size_t)104800256)    // float * NE*32 = 12,800,000
#define OFF_A     ((size_t)117600256)    // float * 2048
#define OFF_B     ((size_t)117608448)    // float * 2048
#define OFF_C0    ((size_t)117616640)    // float * 64 (+pad)
#define WS_NEED   ((size_t)117616896)

__device__ __forceinline__ float frcp(float x){ return __builtin_amdgcn_rcpf(x); }
__device__ __forceinline__ float sigf(float x){ return frcp(1.f + __expf(-x)); }
__device__ __forceinline__ float tanhf_(float x){ return 1.f - 2.f*frcp(__expf(2.f*x) + 1.f); }
__device__ __forceinline__ float4 ld4(const float* p){ return *reinterpret_cast<const float4*>(p); }

// async global->LDS, 16B per lane; LDS dest = (first lane's ptr) + lane*16.
__device__ __forceinline__ void gl16(const float* g, float* l) {
  __builtin_amdgcn_global_load_lds(
      (const __attribute__((address_space(1))) void*)g,
      (__attribute__((address_space(3))) void*)l, 16, 0, 0);
}

// ---------- per-node winner key: max (t, isDst, e) ----------
__global__ void k_scatter(const int* __restrict__ src, const int* __restrict__ dst,
                          const int* __restrict__ t, u64* __restrict__ key) {
  int e = blockIdx.x*256 + threadIdx.x;
  if (e >= NE) return;
  u64 tt = (u64)(unsigned)(t[e] + 1);
  atomicMax(&key[src[e]], (tt<<18) | (u64)(unsigned)e);
  atomicMax(&key[dst[e]], (tt<<18) | (1ULL<<17) | (u64)(unsigned)e);
}

__global__ void k_compact(const u64* __restrict__ key, int* __restrict__ list,
                          int* __restrict__ count) {
  int n = blockIdx.x*256 + threadIdx.x;
  if (n >= NN) return;
  if (key[n] != 0ULL) { int p = atomicAdd(count, 1); list[p] = n; }
}

// ---------- fold W1/W_sp/W_pp/biases: A=W1a@W_sp, B=(W1b+W1c)@W_pp, c0 ----------
__global__ void k_pre(const float* __restrict__ W1, const float* __restrict__ W_sp,
                      const float* __restrict__ W_pp, const float* __restrict__ b_sp,
                      const float* __restrict__ b_pp, const float* __restrict__ b1,
                      float* __restrict__ A, float* __restrict__ B, float* __restrict__ c0)
{
  int tid = blockIdx.x*256 + threadIdx.x;
  if (tid < 2048) {
    int o = tid >> 5, j = tid & 31;
    float s = 0.f;
    for (int k = 0; k < 128; ++k) s = fmaf(W1[o*NG + k], W_sp[k*32 + j], s);
    A[tid] = s;
  } else if (tid < 4096) {
    int q = tid - 2048;
    int o = q >> 5, j = q & 31;
    float s = 0.f;
    for (int k = 0; k < 128; ++k)
      s = fmaf(W1[o*NG + 128 + k] + W1[o*NG + 256 + k], W_pp[k*32 + j], s);
    B[q] = s;
  } else if (tid < 4160) {
    int o = tid - 4096;
    float s = b1[o];
    for (int k = 0; k < 128; ++k) {
      s = fmaf(W1[o*NG + k], b_sp[k], s);
      s = fmaf(W1[o*NG + 128 + k] + W1[o*NG + 256 + k], b_pp[k], s);
    }
    c0[o] = s;
  }
}

// ---------- GRU: 64 nodes/block, 512 thr, 4 nodes/thread + gl_lds W staging ----------
// Live regs ~105 (acc 64 + xv 16 + addr ~25) fits the empirical 128 cap of (512,2)
// (cap law observed r5-r7: cap = 256/arg2, block-size independent). W staging via
// global_load_lds costs zero data registers; source index pre-swizzled (m173).
__global__ __launch_bounds__(512, 2) void k_gru(
    const u64* __restrict__ key, const int* __restrict__ list, const int* __restrict__ count,
    const int* __restrict__ src, const int* __restrict__ dst, const int* __restrict__ t,
    const float* __restrict__ msg, const float* __restrict__ memory,
    const float* __restrict__ last_update,
    const float* __restrict__ w_t, const float* __restrict__ b_t,
    const float* __restrict__ W_ih, const float* __restrict__ b_ih,
    const float* __restrict__ W_hh, const float* __restrict__ b_hh,
    const float* __restrict__ W1, float* __restrict__ uv)
{
  __shared__ float Ws[12288];          // [384 g][32 k], XOR-swizzled quads (48KB)
  __shared__ float Xs[2048];           // [64 node][32 k] chunk (8KB)
  __shared__ int   sn_self[64];
  __shared__ int   sn_other[64];
  __shared__ int   sn_e[64];
  __shared__ float sn_dt[64];

  int cnt = count[0];
  int base = blockIdx.x * 64;
  if (base >= cnt) return;
  int tid = threadIdx.x;
  int tx = tid & 31, ty = tid >> 5;    // ty 0..15

  if (tid < 64) {
    int idx = base + tid;
    int cl = idx < cnt ? idx : (cnt - 1);
    int n = list[cl];
    u64 k = key[n];
    int e   = (int)(k & 0x1FFFFULL);
    int isd = (int)((k >> 17) & 1ULL);
    sn_self[tid]  = n;
    sn_other[tid] = isd ? src[e] : dst[e];
    sn_e[tid]     = e;
    sn_dt[tid]    = (float)t[e] - last_update[n];
  }
  __syncthreads();

  float acc[4][12];
  float accN[4][4];
  #pragma unroll
  for (int a=0;a<4;++a){
    #pragma unroll
    for (int b=0;b<12;++b) acc[a][b]=0.f;
    #pragma unroll
    for (int b=0;b<4;++b) accN[a][b]=0.f;
  }

  for (int ch = 0; ch < 18; ++ch) {
    // W chunk: 3072 quads via global_load_lds (6 calls x 512 lanes), zero data regs.
    // LDS slot q holds (g=q>>3, k4=(q&7)^(g&7)) -> matches the read-side swizzle.
    #pragma unroll
    for (int i = 0; i < 6; ++i) {
      int q = i*512 + tid;
      int g = q >> 3;
      int k4 = (q & 7) ^ (g & 7);
      int k = ch*32 + k4*4;
      const float* srcp = (k < 448) ? (W_ih + (size_t)g*448 + k)
                                    : (W_hh + (size_t)g*HD + (k-448));
      gl16(srcp, &Ws[q*4]);
    }
    // X chunk: 64 nodes x 32 k = 512 float4, 1 per thread
    {
      int nodeL = tid >> 3, k4 = tid & 7;
      int k = ch*32 + k4*4;
      int self = sn_self[nodeL], other = sn_other[nodeL], e = sn_e[nodeL];
      float4 vx;
      if (k < 128)      vx = ld4(memory + (size_t)self*HD + k);
      else if (k < 256) vx = ld4(memory + (size_t)other*HD + (k-128));
      else if (k < 320) vx = ld4(msg + (size_t)e*EFD + (k-256));
      else if (k < 448) {
        int kk = k - 320; float dt = sn_dt[nodeL];
        vx.x = cosf(fmaf(dt, w_t[kk],   b_t[kk]));
        vx.y = cosf(fmaf(dt, w_t[kk+1], b_t[kk+1]));
        vx.z = cosf(fmaf(dt, w_t[kk+2], b_t[kk+2]));
        vx.w = cosf(fmaf(dt, w_t[kk+3], b_t[kk+3]));
      } else            vx = ld4(memory + (size_t)self*HD + (k-448));
      *reinterpret_cast<float4*>(&Xs[nodeL*32 + k4*4]) = vx;
    }
    __syncthreads();   // drains vmcnt (global_load_lds) + lgkm

    bool memPart = (ch >= 14);
    #pragma unroll
    for (int k4 = 0; k4 < 8; ++k4) {
      float4 xv[4];
      #pragma unroll
      for (int nn = 0; nn < 4; ++nn)
        xv[nn] = *reinterpret_cast<const float4*>(&Xs[(ty + 16*nn)*32 + k4*4]);
      #pragma unroll
      for (int gg = 0; gg < 12; ++gg) {
        int g = tx + 32*gg;
        float4 w = *reinterpret_cast<const float4*>(&Ws[g*32 + ((k4 ^ (g&7))<<2)]);
        if (gg < 8) {
          #pragma unroll
          for (int nn = 0; nn < 4; ++nn) {
            acc[nn][gg] = fmaf(w.x, xv[nn].x, acc[nn][gg]);
            acc[nn][gg] = fmaf(w.y, xv[nn].y, acc[nn][gg]);
            acc[nn][gg] = fmaf(w.z, xv[nn].z, acc[nn][gg]);
            acc[nn][gg] = fmaf(w.w, xv[nn].w, acc[nn][gg]);
          }
        } else if (!memPart) {
          #pragma unroll
          for (int nn = 0; nn < 4; ++nn) {
            acc[nn][gg] = fmaf(w.x, xv[nn].x, acc[nn][gg]);
            acc[nn][gg] = fmaf(w.y, xv[nn].y, acc[nn][gg]);
            acc[nn][gg] = fmaf(w.z, xv[nn].z, acc[nn][gg]);
            acc[nn][gg] = fmaf(w.w, xv[nn].w, acc[nn][gg]);
          }
        } else {
          #pragma unroll
          for (int nn = 0; nn < 4; ++nn) {
            accN[nn][gg-8] = fmaf(w.x, xv[nn].x, accN[nn][gg-8]);
            accN[nn][gg-8] = fmaf(w.y, xv[nn].y, accN[nn][gg-8]);
            accN[nn][gg-8] = fmaf(w.z, xv[nn].z, accN[nn][gg-8]);
            accN[nn][gg-8] = fmaf(w.w, xv[nn].w, accN[nn][gg-8]);
          }
        }
      }
    }
    __syncthreads();
  }

  // epilogue: GRU gates -> mem_new tile in LDS (overlay Ws[4096..12288))
  float* Mn = &Ws[4096];   // [64][128]
  #pragma unroll
  for (int nn = 0; nn < 4; ++nn) {
    int nl = ty + 16*nn;
    int self = sn_self[nl];
    #pragma unroll
    for (int hh = 0; hh < 4; ++hh) {
      int h = tx + 32*hh;
      float r  = sigf(acc[nn][hh]     + b_ih[h]       + b_hh[h]);
      float z  = sigf(acc[nn][4+hh]   + b_ih[128+h]   + b_hh[128+h]);
      float nv = tanhf_(acc[nn][8+hh] + b_ih[256+h] + r*(accN[nn][hh] + b_hh[256+h]));
      float m  = memory[(size_t)self*HD + h];
      Mn[nl*128 + h] = (1.f - z)*nv + z*m;
    }
  }
  __syncthreads();

  // uv = [W1a@mn | W1b@mn] : K=128 chunked by 32, W1 chunk staged at Ws[0..4096)
  float acc2[4][4];
  #pragma unroll
  for (int a=0;a<4;++a){
    #pragma unroll
    for (int b=0;b<4;++b) acc2[a][b]=0.f;
  }
  for (int ch = 0; ch < 4; ++ch) {
    #pragma unroll
    for (int i = 0; i < 2; ++i) {
      int idx = tid + 512*i;
      int o = idx >> 3, k4 = idx & 7;
      int k = ch*32 + k4*4;
      float4 w = (o < 64) ? ld4(W1 + (size_t)o*NG + k)
                          : ld4(W1 + (size_t)(o-64)*NG + 128 + k);
      *reinterpret_cast<float4*>(&Ws[o*32 + ((k4 ^ (o&7))<<2)]) = w;
    }
    __syncthreads();
    #pragma unroll
    for (int k4 = 0; k4 < 8; ++k4) {
      float4 xv[4];
      #pragma unroll
      for (int nn = 0; nn < 4; ++nn)
        xv[nn] = *reinterpret_cast<const float4*>(&Mn[(ty+16*nn)*128 + ch*32 + k4*4]);
      #pragma unroll
      for (int og = 0; og < 4; ++og) {
        int o = tx + 32*og;
        float4 w = *reinterpret_cast<const float4*>(&Ws[o*32 + ((k4 ^ (o&7))<<2)]);
        #pragma unroll
        for (int nn = 0; nn < 4; ++nn) {
          acc2[nn][og] = fmaf(w.x, xv[nn].x, acc2[nn][og]);
          acc2[nn][og] = fmaf(w.y, xv[nn].y, acc2[nn][og]);
          acc2[nn][og] = fmaf(w.z, xv[nn].z, acc2[nn][og]);
          acc2[nn][og] = fmaf(w.w, xv[nn].w, acc2[nn][og]);
        }
      }
    }
    __syncthreads();
  }
  #pragma unroll
  for (int nn = 0; nn < 4; ++nn) {
    int nl = ty + 16*nn;
    if (base + nl < cnt) {
      int self = sn_self[nl];
      #pragma unroll
      for (int og = 0; og < 4; ++og)
        uv[(size_t)self*128 + tx + 32*og] = acc2[nn][og];
    }
  }
}

// ---------- price LSTM: thread (g,j) owns hidden unit j of edge g ----------
__global__ __launch_bounds__(256) void k_lstm(
    const float* __restrict__ price, const float* __restrict__ W_ihl,
    const float* __restrict__ W_hhl, const float* __restrict__ b_ihl,
    const float* __restrict__ b_hhl, float* __restrict__ hn_out)
{
  __shared__ float Wsh[4096];     // W_hh row-major [128][32] = 16KB
  __shared__ float ps[8][52];     // price rows (pad to 52)
  __shared__ float hrow[8][36];   // h per edge (stride 36)
  int tid = threadIdx.x;
  int g = tid >> 5;               // edge slot 0..7
  int j = tid & 31;               // hidden unit

  for (int i = tid; i < 1024; i += 256)
    *reinterpret_cast<float4*>(&Wsh[i*4]) = ld4(W_hhl + i*4);
  {
    int ebase = blockIdx.x*8;
    int m = NE - ebase; if (m > 8) m = 8;
    const float* pb = price + (size_t)ebase*50;
    for (int i = tid; i < m*50; i += 256) ps[i/50][i%50] = pb[i];
  }
  __syncthreads();

  float wi[32], wf[32], wg[32], wo[32];
  #pragma unroll
  for (int k = 0; k < 32; ++k) {
    wi[k] = Wsh[j*32 + k];
    wf[k] = Wsh[(32+j)*32 + k];
    wg[k] = Wsh[(64+j)*32 + k];
    wo[k] = Wsh[(96+j)*32 + k];
  }
  float wxi = W_ihl[j],    wxf = W_ihl[32+j], wxg = W_ihl[64+j], wxo = W_ihl[96+j];
  float bi  = b_ihl[j]    + b_hhl[j];
  float bf  = b_ihl[32+j] + b_hhl[32+j];
  float bg  = b_ihl[64+j] + b_hhl[64+j];
  float bo  = b_ihl[96+j] + b_hhl[96+j];

  float c = 0.f, hlast = 0.f;
  hrow[g][j] = 0.f;
  __syncthreads();

  #pragma unroll 1
  for (int s = 0; s < 50; ++s) {
    float x = ps[g][s];
    float ai = fmaf(x, wxi, bi);
    float af = fmaf(x, wxf, bf);
    float ag = fmaf(x, wxg, bg);
    float ao = fmaf(x, wxo, bo);
    #pragma unroll
    for (int k4 = 0; k4 < 8; ++k4) {
      float4 hv = *reinterpret_cast<const float4*>(&hrow[g][k4*4]);
      int b = k4*4;
      ai = fmaf(wi[b],hv.x, fmaf(wi[b+1],hv.y, fmaf(wi[b+2],hv.z, fmaf(wi[b+3],hv.w, ai))));
      af = fmaf(wf[b],hv.x, fmaf(wf[b+1],hv.y, fmaf(wf[b+2],hv.z, fmaf(wf[b+3],hv.w, af))));
      ag = fmaf(wg[b],hv.x, fmaf(wg[b+1],hv.y, fmaf(wg[b+2],hv.z, fmaf(wg[b+3],hv.w, ag))));
      ao = fmaf(wo[b],hv.x, fmaf(wo[b+1],hv.y, fmaf(wo[b+2],hv.z, fmaf(wo[b+3],hv.w, ao))));
    }
    float ig = sigf(ai), fg = sigf(af), gv = tanhf_(ag), og = sigf(ao);
    c = fmaf(fg, c, ig*gv);
    hlast = og * tanhf_(c);
    hrow[g][j] = hlast;
  }

  int e = blockIdx.x*8 + g;
  if (e < NE) hn_out[(size_t)e*32 + j] = hlast;
}

// ---------- fused output: out = W2 @ relu(u[s] + v[d] + A@sf + B@hn + c0) + b2 ----------
__global__ __launch_bounds__(256) void k_final(
    const int* __restrict__ src, const int* __restrict__ dst, const int* __restrict__ xst,
    const float* __restrict__ party, const float* __restrict__ state,
    const float* __restrict__ uv, const float* __restrict__ hn,
    const float* __restrict__ A, const float* __restrict__ B, const float* __restrict__ c0,
    const float* __restrict__ W2, const float* __restrict__ b2, float* __restrict__ out)
{
  __shared__ float As[2048], Bs[2048], c0s[64], W2s[64];
  int tid = threadIdx.x;
  for (int i = tid; i < 2048; i += 256) { As[i] = A[i]; Bs[i] = B[i]; }
  if (tid < 64) { c0s[tid] = c0[tid]; W2s[tid] = W2[tid]; }
  __syncthreads();
  int e = blockIdx.x*256 + tid;
  if (e >= NE) return;
  int s = src[e], d = dst[e];
  int p = xst[2*s], stt = xst[2*s + 1];
  float4 sf4[8], hv4[8];
  #pragma unroll
  for (int i = 0; i < 4; ++i) sf4[i]   = ld4(party + p*16 + i*4);
  #pragma unroll
  for (int i = 0; i < 4; ++i) sf4[4+i] = ld4(state + stt*16 + i*4);
  #pragma unroll
  for (int i = 0; i < 8; ++i) hv4[i] = ld4(hn + (size_t)e*32 + i*4);
  const float* urow = uv + (size_t)s*128;
  const float* vrow = uv + (size_t)d*128 + 64;
  float oacc = b2[0];
  #pragma unroll 4
  for (int o4 = 0; o4 < 16; ++o4) {
    float4 u4 = ld4(urow + o4*4);
    float4 v4 = ld4(vrow + o4*4);
    float4 cc = *reinterpret_cast<const float4*>(&c0s[o4*4]);
    float4 w2 = *reinterpret_cast<const float4*>(&W2s[o4*4]);
    float hh[4] = {u4.x+v4.x+cc.x, u4.y+v4.y+cc.y, u4.z+v4.z+cc.z, u4.w+v4.w+cc.w};
    #pragma unroll
    for (int oo = 0; oo < 4; ++oo) {
      int o = o4*4 + oo;
      float acc = hh[oo];
      #pragma unroll
      for (int j4 = 0; j4 < 8; ++j4) {
        float4 a = *reinterpret_cast<const float4*>(&As[o*32 + j4*4]);
        float4 b = *reinterpret_cast<const float4*>(&Bs[o*32 + j4*4]);
        float4 sfv = sf4[j4], hvv = hv4[j4];
        acc = fmaf(a.x,sfv.x, fmaf(a.y,sfv.y, fmaf(a.z,sfv.z, fmaf(a.w,sfv.w, acc))));
        acc = fmaf(b.x,hvv.x, fmaf(b.y,hvv.y, fmaf(b.z,hvv.z, fmaf(b.w,hvv.w, acc))));
      }
      float w2v = (oo==0) ? w2.x : (oo==1) ? w2.y : (oo==2) ? w2.z : w2.w;
      oacc = fmaf(w2v, fmaxf(acc, 0.f), oacc);
    }
  }
  out[e] = oacc;
}

extern "C" void kernel_launch(void* const* d_in, const int* in_sizes, int n_in,
                              void* d_out, int out_size, void* d_ws, size_t ws_size,
                              hipStream_t stream) {
  const int*   src   = (const int*)d_in[0];
  const int*   dst   = (const int*)d_in[1];
  const int*   t     = (const int*)d_in[2];
  const float* msg   = (const float*)d_in[3];
  const float* price = (const float*)d_in[4];
  // d_in[5] trade_t: unused by reference
  const int*   xst   = (const int*)d_in[6];
  const float* memory= (const float*)d_in[7];
  const float* lu    = (const float*)d_in[8];
  const float* w_t   = (const float*)d_in[9];
  const float* b_t   = (const float*)d_in[10];
  const float* W_ih  = (const float*)d_in[11];
  const float* b_ih  = (const float*)d_in[12];
  const float* W_hh  = (const float*)d_in[13];
  const float* b_hh  = (const float*)d_in[14];
  const float* party = (const float*)d_in[15];
  const float* state = (const float*)d_in[16];
  const float* W_sp  = (const float*)d_in[17];
  const float* b_sp  = (const float*)d_in[18];
  const float* W_ihl = (const float*)d_in[19];
  const float* W_hhl = (const float*)d_in[20];
  const float* b_ihl = (const float*)d_in[21];
  const float* b_hhl = (const float*)d_in[22];
  const float* W_pp  = (const float*)d_in[23];
  const float* b_pp  = (const float*)d_in[24];
  const float* W1    = (const float*)d_in[25];
  const float* b1    = (const float*)d_in[26];
  const float* W2    = (const float*)d_in[27];
  const float* b2    = (const float*)d_in[28];
  float* out = (float*)d_out;

  if (ws_size < WS_NEED) {              // loud failure: zero output
    (void)hipMemsetAsync(d_out, 0, (size_t)out_size*4, stream);
    return;
  }

  char* ws = (char*)d_ws;
  u64*   key  = (u64*)(ws + OFF_KEY);
  int*   cnt  = (int*)(ws + OFF_CNT);
  int*   list = (int*)(ws + OFF_LIST);
  float* uv   = (float*)(ws + OFF_UV);
  float* hn   = (float*)(ws + OFF_HN);
  float* A    = (float*)(ws + OFF_A);
  float* B    = (float*)(ws + OFF_B);
  float* c0   = (float*)(ws + OFF_C0);

  (void)hipMemsetAsync(ws, 0, OFF_LIST, stream);   // zero key[] + count
  k_scatter<<<(NE+255)/256, 256, 0, stream>>>(src, dst, t, key);
  k_compact<<<(NN+255)/256, 256, 0, stream>>>(key, list, cnt);
  k_pre<<<17, 256, 0, stream>>>(W1, W_sp, W_pp, b_sp, b_pp, b1, A, B, c0);
  k_lstm<<<(NE+7)/8, 256, 0, stream>>>(price, W_ihl, W_hhl, b_ihl, b_hhl, hn);
  k_gru<<<(NN+63)/64, 512, 0, stream>>>(key, list, cnt, src, dst, t, msg, memory, lu,
                                        w_t, b_t, W_ih, b_ih, W_hh, b_hh, W1, uv);
  k_final<<<(NE+255)/256, 256, 0, stream>>>(src, dst, xst, party, state, uv, hn,
                                            A, B, c0, W2, b2, out);
}

// Round 9
// 1963.100 us; speedup vs baseline: 5.3768x; 3.7969x over previous
//
#include <hip/hip_runtime.h>
#include <stdint.h>

#define NN    200000   // nodes
#define NE    100000   // edges
#define HD    128      // hidden/memory/time dim
#define EFD   64       // edge feat dim
#define NG    384      // 3*HD gates

typedef unsigned long long u64;

// ---- ws layout (bytes) ----
#define OFF_KEY   ((size_t)0)            // u64 * NN = 1,600,000
#define OFF_CNT   ((size_t)1600000)      // int
#define OFF_LIST  ((size_t)1600256)      // int * NN = 800,000
#define OFF_UV    ((size_t)2400256)      // float * NN*128 = 102,400,000
#define OFF_HN    ((size_t)104800256)    // float * NE*32 = 12,800,000
#define OFF_A     ((size_t)117600256)    // float * 2048
#define OFF_B     ((size_t)117608448)    // float * 2048
#define OFF_C0    ((size_t)117616640)    // float * 64 (+pad)
#define WS_NEED   ((size_t)117616896)

__device__ __forceinline__ float frcp(float x){ return __builtin_amdgcn_rcpf(x); }
__device__ __forceinline__ float sigf(float x){ return frcp(1.f + __expf(-x)); }
__device__ __forceinline__ float tanhf_(float x){ return 1.f - 2.f*frcp(__expf(2.f*x) + 1.f); }
__device__ __forceinline__ float4 ld4(const float* p){ return *reinterpret_cast<const float4*>(p); }

// async global->LDS, 16B per lane; LDS dest = (first lane's ptr) + lane*16.
__device__ __forceinline__ void gl16(const float* g, float* l) {
  __builtin_amdgcn_global_load_lds(
      (const __attribute__((address_space(1))) void*)g,
      (__attribute__((address_space(3))) void*)l, 16, 0, 0);
}

// ---------- per-node winner key: max (t, isDst, e) ----------
__global__ void k_scatter(const int* __restrict__ src, const int* __restrict__ dst,
                          const int* __restrict__ t, u64* __restrict__ key) {
  int e = blockIdx.x*256 + threadIdx.x;
  if (e >= NE) return;
  u64 tt = (u64)(unsigned)(t[e] + 1);
  atomicMax(&key[src[e]], (tt<<18) | (u64)(unsigned)e);
  atomicMax(&key[dst[e]], (tt<<18) | (1ULL<<17) | (u64)(unsigned)e);
}

__global__ void k_compact(const u64* __restrict__ key, int* __restrict__ list,
                          int* __restrict__ count) {
  int n = blockIdx.x*256 + threadIdx.x;
  if (n >= NN) return;
  if (key[n] != 0ULL) { int p = atomicAdd(count, 1); list[p] = n; }
}

// ---------- fold W1/W_sp/W_pp/biases: A=W1a@W_sp, B=(W1b+W1c)@W_pp, c0 ----------
__global__ void k_pre(const float* __restrict__ W1, const float* __restrict__ W_sp,
                      const float* __restrict__ W_pp, const float* __restrict__ b_sp,
                      const float* __restrict__ b_pp, const float* __restrict__ b1,
                      float* __restrict__ A, float* __restrict__ B, float* __restrict__ c0)
{
  int tid = blockIdx.x*256 + threadIdx.x;
  if (tid < 2048) {
    int o = tid >> 5, j = tid & 31;
    float s = 0.f;
    for (int k = 0; k < 128; ++k) s = fmaf(W1[o*NG + k], W_sp[k*32 + j], s);
    A[tid] = s;
  } else if (tid < 4096) {
    int q = tid - 2048;
    int o = q >> 5, j = q & 31;
    float s = 0.f;
    for (int k = 0; k < 128; ++k)
      s = fmaf(W1[o*NG + 128 + k] + W1[o*NG + 256 + k], W_pp[k*32 + j], s);
    B[q] = s;
  } else if (tid < 4160) {
    int o = tid - 4096;
    float s = b1[o];
    for (int k = 0; k < 128; ++k) {
      s = fmaf(W1[o*NG + k], b_sp[k], s);
      s = fmaf(W1[o*NG + 128 + k] + W1[o*NG + 256 + k], b_pp[k], s);
    }
    c0[o] = s;
  }
}

// ---------- GRU: 64 nodes/block, 512 thr, 4 nodes/thread ----------
// RULE #20 FIX: no runtime-conditional accumulator selection. The memPart flag is
// hoisted into two fully-static code paths (ch<14 vs ch>=14) so every acc/accN
// index is a compile-time constant -> arrays stay in VGPRs, no scratch.
__global__ __launch_bounds__(512, 2) void k_gru(
    const u64* __restrict__ key, const int* __restrict__ list, const int* __restrict__ count,
    const int* __restrict__ src, const int* __restrict__ dst, const int* __restrict__ t,
    const float* __restrict__ msg, const float* __restrict__ memory,
    const float* __restrict__ last_update,
    const float* __restrict__ w_t, const float* __restrict__ b_t,
    const float* __restrict__ W_ih, const float* __restrict__ b_ih,
    const float* __restrict__ W_hh, const float* __restrict__ b_hh,
    const float* __restrict__ W1, float* __restrict__ uv)
{
  __shared__ float Ws[12288];          // [384 g][32 k], XOR-swizzled quads (48KB)
  __shared__ float Xs[2048];           // [64 node][32 k] chunk (8KB)
  __shared__ int   sn_self[64];
  __shared__ int   sn_other[64];
  __shared__ int   sn_e[64];
  __shared__ float sn_dt[64];

  int cnt = count[0];
  int base = blockIdx.x * 64;
  if (base >= cnt) return;
  int tid = threadIdx.x;
  int tx = tid & 31, ty = tid >> 5;    // ty 0..15

  if (tid < 64) {
    int idx = base + tid;
    int cl = idx < cnt ? idx : (cnt - 1);
    int n = list[cl];
    u64 k = key[n];
    int e   = (int)(k & 0x1FFFFULL);
    int isd = (int)((k >> 17) & 1ULL);
    sn_self[tid]  = n;
    sn_other[tid] = isd ? src[e] : dst[e];
    sn_e[tid]     = e;
    sn_dt[tid]    = (float)t[e] - last_update[n];
  }
  __syncthreads();

  float acc[4][12];
  float accN[4][4];
  #pragma unroll
  for (int a=0;a<4;++a){
    #pragma unroll
    for (int b=0;b<12;++b) acc[a][b]=0.f;
    #pragma unroll
    for (int b=0;b<4;++b) accN[a][b]=0.f;
  }

  for (int ch = 0; ch < 18; ++ch) {
    // W chunk: 3072 quads via global_load_lds (6 calls x 512 lanes), zero data regs.
    #pragma unroll
    for (int i = 0; i < 6; ++i) {
      int q = i*512 + tid;
      int g = q >> 3;
      int k4 = (q & 7) ^ (g & 7);
      int k = ch*32 + k4*4;
      const float* srcp = (k < 448) ? (W_ih + (size_t)g*448 + k)
                                    : (W_hh + (size_t)g*HD + (k-448));
      gl16(srcp, &Ws[q*4]);
    }
    // X chunk: 64 nodes x 32 k = 512 float4, 1 per thread
    {
      int nodeL = tid >> 3, k4 = tid & 7;
      int k = ch*32 + k4*4;
      int self = sn_self[nodeL], other = sn_other[nodeL], e = sn_e[nodeL];
      float4 vx;
      if (k < 128)      vx = ld4(memory + (size_t)self*HD + k);
      else if (k < 256) vx = ld4(memory + (size_t)other*HD + (k-128));
      else if (k < 320) vx = ld4(msg + (size_t)e*EFD + (k-256));
      else if (k < 448) {
        int kk = k - 320; float dt = sn_dt[nodeL];
        vx.x = cosf(fmaf(dt, w_t[kk],   b_t[kk]));
        vx.y = cosf(fmaf(dt, w_t[kk+1], b_t[kk+1]));
        vx.z = cosf(fmaf(dt, w_t[kk+2], b_t[kk+2]));
        vx.w = cosf(fmaf(dt, w_t[kk+3], b_t[kk+3]));
      } else            vx = ld4(memory + (size_t)self*HD + (k-448));
      *reinterpret_cast<float4*>(&Xs[nodeL*32 + k4*4]) = vx;
    }
    __syncthreads();   // drains vmcnt (global_load_lds) + lgkm

    if (ch < 14) {
      // ---- static path A: all 12 gate-groups accumulate into acc ----
      #pragma unroll
      for (int k4 = 0; k4 < 8; ++k4) {
        float4 xv[4];
        #pragma unroll
        for (int nn = 0; nn < 4; ++nn)
          xv[nn] = *reinterpret_cast<const float4*>(&Xs[(ty + 16*nn)*32 + k4*4]);
        #pragma unroll
        for (int gg = 0; gg < 12; ++gg) {
          int g = tx + 32*gg;
          float4 w = *reinterpret_cast<const float4*>(&Ws[g*32 + ((k4 ^ (g&7))<<2)]);
          #pragma unroll
          for (int nn = 0; nn < 4; ++nn) {
            acc[nn][gg] = fmaf(w.x, xv[nn].x, acc[nn][gg]);
            acc[nn][gg] = fmaf(w.y, xv[nn].y, acc[nn][gg]);
            acc[nn][gg] = fmaf(w.z, xv[nn].z, acc[nn][gg]);
            acc[nn][gg] = fmaf(w.w, xv[nn].w, acc[nn][gg]);
          }
        }
      }
    } else {
      // ---- static path B: gg 0..7 -> acc, gg 8..11 -> accN (memory-part of n-gate) ----
      #pragma unroll
      for (int k4 = 0; k4 < 8; ++k4) {
        float4 xv[4];
        #pragma unroll
        for (int nn = 0; nn < 4; ++nn)
          xv[nn] = *reinterpret_cast<const float4*>(&Xs[(ty + 16*nn)*32 + k4*4]);
        #pragma unroll
        for (int gg = 0; gg < 8; ++gg) {
          int g = tx + 32*gg;
          float4 w = *reinterpret_cast<const float4*>(&Ws[g*32 + ((k4 ^ (g&7))<<2)]);
          #pragma unroll
          for (int nn = 0; nn < 4; ++nn) {
            acc[nn][gg] = fmaf(w.x, xv[nn].x, acc[nn][gg]);
            acc[nn][gg] = fmaf(w.y, xv[nn].y, acc[nn][gg]);
            acc[nn][gg] = fmaf(w.z, xv[nn].z, acc[nn][gg]);
            acc[nn][gg] = fmaf(w.w, xv[nn].w, acc[nn][gg]);
          }
        }
        #pragma unroll
        for (int gg = 8; gg < 12; ++gg) {
          int g = tx + 32*gg;
          float4 w = *reinterpret_cast<const float4*>(&Ws[g*32 + ((k4 ^ (g&7))<<2)]);
          #pragma unroll
          for (int nn = 0; nn < 4; ++nn) {
            accN[nn][gg-8] = fmaf(w.x, xv[nn].x, accN[nn][gg-8]);
            accN[nn][gg-8] = fmaf(w.y, xv[nn].y, accN[nn][gg-8]);
            accN[nn][gg-8] = fmaf(w.z, xv[nn].z, accN[nn][gg-8]);
            accN[nn][gg-8] = fmaf(w.w, xv[nn].w, accN[nn][gg-8]);
          }
        }
      }
    }
    __syncthreads();
  }

  // epilogue: GRU gates -> mem_new tile in LDS (overlay Ws[4096..12288))
  float* Mn = &Ws[4096];   // [64][128]
  #pragma unroll
  for (int nn = 0; nn < 4; ++nn) {
    int nl = ty + 16*nn;
    int self = sn_self[nl];
    #pragma unroll
    for (int hh = 0; hh < 4; ++hh) {
      int h = tx + 32*hh;
      float r  = sigf(acc[nn][hh]     + b_ih[h]       + b_hh[h]);
      float z  = sigf(acc[nn][4+hh]   + b_ih[128+h]   + b_hh[128+h]);
      float nv = tanhf_(acc[nn][8+hh] + b_ih[256+h] + r*(accN[nn][hh] + b_hh[256+h]));
      float m  = memory[(size_t)self*HD + h];
      Mn[nl*128 + h] = (1.f - z)*nv + z*m;
    }
  }
  __syncthreads();

  // uv = [W1a@mn | W1b@mn] : K=128 chunked by 32, W1 chunk staged at Ws[0..4096)
  float acc2[4][4];
  #pragma unroll
  for (int a=0;a<4;++a){
    #pragma unroll
    for (int b=0;b<4;++b) acc2[a][b]=0.f;
  }
  for (int ch = 0; ch < 4; ++ch) {
    #pragma unroll
    for (int i = 0; i < 2; ++i) {
      int idx = tid + 512*i;
      int o = idx >> 3, k4 = idx & 7;
      int k = ch*32 + k4*4;
      float4 w = (o < 64) ? ld4(W1 + (size_t)o*NG + k)
                          : ld4(W1 + (size_t)(o-64)*NG + 128 + k);
      *reinterpret_cast<float4*>(&Ws[o*32 + ((k4 ^ (o&7))<<2)]) = w;
    }
    __syncthreads();
    #pragma unroll
    for (int k4 = 0; k4 < 8; ++k4) {
      float4 xv[4];
      #pragma unroll
      for (int nn = 0; nn < 4; ++nn)
        xv[nn] = *reinterpret_cast<const float4*>(&Mn[(ty+16*nn)*128 + ch*32 + k4*4]);
      #pragma unroll
      for (int og = 0; og < 4; ++og) {
        int o = tx + 32*og;
        float4 w = *reinterpret_cast<const float4*>(&Ws[o*32 + ((k4 ^ (o&7))<<2)]);
        #pragma unroll
        for (int nn = 0; nn < 4; ++nn) {
          acc2[nn][og] = fmaf(w.x, xv[nn].x, acc2[nn][og]);
          acc2[nn][og] = fmaf(w.y, xv[nn].y, acc2[nn][og]);
          acc2[nn][og] = fmaf(w.z, xv[nn].z, acc2[nn][og]);
          acc2[nn][og] = fmaf(w.w, xv[nn].w, acc2[nn][og]);
        }
      }
    }
    __syncthreads();
  }
  #pragma unroll
  for (int nn = 0; nn < 4; ++nn) {
    int nl = ty + 16*nn;
    if (base + nl < cnt) {
      int self = sn_self[nl];
      #pragma unroll
      for (int og = 0; og < 4; ++og)
        uv[(size_t)self*128 + tx + 32*og] = acc2[nn][og];
    }
  }
}

// ---------- price LSTM: thread (g,j) owns hidden unit j of edge g ----------
__global__ __launch_bounds__(256) void k_lstm(
    const float* __restrict__ price, const float* __restrict__ W_ihl,
    const float* __restrict__ W_hhl, const float* __restrict__ b_ihl,
    const float* __restrict__ b_hhl, float* __restrict__ hn_out)
{
  __shared__ float Wsh[4096];     // W_hh row-major [128][32] = 16KB
  __shared__ float ps[8][52];     // price rows (pad to 52)
  __shared__ float hrow[8][36];   // h per edge (stride 36)
  int tid = threadIdx.x;
  int g = tid >> 5;               // edge slot 0..7
  int j = tid & 31;               // hidden unit

  for (int i = tid; i < 1024; i += 256)
    *reinterpret_cast<float4*>(&Wsh[i*4]) = ld4(W_hhl + i*4);
  {
    int ebase = blockIdx.x*8;
    int m = NE - ebase; if (m > 8) m = 8;
    const float* pb = price + (size_t)ebase*50;
    for (int i = tid; i < m*50; i += 256) ps[i/50][i%50] = pb[i];
  }
  __syncthreads();

  float wi[32], wf[32], wg[32], wo[32];
  #pragma unroll
  for (int k = 0; k < 32; ++k) {
    wi[k] = Wsh[j*32 + k];
    wf[k] = Wsh[(32+j)*32 + k];
    wg[k] = Wsh[(64+j)*32 + k];
    wo[k] = Wsh[(96+j)*32 + k];
  }
  float wxi = W_ihl[j],    wxf = W_ihl[32+j], wxg = W_ihl[64+j], wxo = W_ihl[96+j];
  float bi  = b_ihl[j]    + b_hhl[j];
  float bf  = b_ihl[32+j] + b_hhl[32+j];
  float bg  = b_ihl[64+j] + b_hhl[64+j];
  float bo  = b_ihl[96+j] + b_hhl[96+j];

  float c = 0.f, hlast = 0.f;
  hrow[g][j] = 0.f;
  __syncthreads();

  #pragma unroll 1
  for (int s = 0; s < 50; ++s) {
    float x = ps[g][s];
    float ai = fmaf(x, wxi, bi);
    float af = fmaf(x, wxf, bf);
    float ag = fmaf(x, wxg, bg);
    float ao = fmaf(x, wxo, bo);
    #pragma unroll
    for (int k4 = 0; k4 < 8; ++k4) {
      float4 hv = *reinterpret_cast<const float4*>(&hrow[g][k4*4]);
      int b = k4*4;
      ai = fmaf(wi[b],hv.x, fmaf(wi[b+1],hv.y, fmaf(wi[b+2],hv.z, fmaf(wi[b+3],hv.w, ai))));
      af = fmaf(wf[b],hv.x, fmaf(wf[b+1],hv.y, fmaf(wf[b+2],hv.z, fmaf(wf[b+3],hv.w, af))));
      ag = fmaf(wg[b],hv.x, fmaf(wg[b+1],hv.y, fmaf(wg[b+2],hv.z, fmaf(wg[b+3],hv.w, ag))));
      ao = fmaf(wo[b],hv.x, fmaf(wo[b+1],hv.y, fmaf(wo[b+2],hv.z, fmaf(wo[b+3],hv.w, ao))));
    }
    float ig = sigf(ai), fg = sigf(af), gv = tanhf_(ag), og = sigf(ao);
    c = fmaf(fg, c, ig*gv);
    hlast = og * tanhf_(c);
    hrow[g][j] = hlast;
  }

  int e = blockIdx.x*8 + g;
  if (e < NE) hn_out[(size_t)e*32 + j] = hlast;
}

// ---------- fused output: out = W2 @ relu(u[s] + v[d] + A@sf + B@hn + c0) + b2 ----------
__global__ __launch_bounds__(256) void k_final(
    const int* __restrict__ src, const int* __restrict__ dst, const int* __restrict__ xst,
    const float* __restrict__ party, const float* __restrict__ state,
    const float* __restrict__ uv, const float* __restrict__ hn,
    const float* __restrict__ A, const float* __restrict__ B, const float* __restrict__ c0,
    const float* __restrict__ W2, const float* __restrict__ b2, float* __restrict__ out)
{
  __shared__ float As[2048], Bs[2048], c0s[64], W2s[64];
  int tid = threadIdx.x;
  for (int i = tid; i < 2048; i += 256) { As[i] = A[i]; Bs[i] = B[i]; }
  if (tid < 64) { c0s[tid] = c0[tid]; W2s[tid] = W2[tid]; }
  __syncthreads();
  int e = blockIdx.x*256 + tid;
  if (e >= NE) return;
  int s = src[e], d = dst[e];
  int p = xst[2*s], stt = xst[2*s + 1];
  float4 sf4[8], hv4[8];
  #pragma unroll
  for (int i = 0; i < 4; ++i) sf4[i]   = ld4(party + p*16 + i*4);
  #pragma unroll
  for (int i = 0; i < 4; ++i) sf4[4+i] = ld4(state + stt*16 + i*4);
  #pragma unroll
  for (int i = 0; i < 8; ++i) hv4[i] = ld4(hn + (size_t)e*32 + i*4);
  const float* urow = uv + (size_t)s*128;
  const float* vrow = uv + (size_t)d*128 + 64;
  float oacc = b2[0];
  #pragma unroll 4
  for (int o4 = 0; o4 < 16; ++o4) {
    float4 u4 = ld4(urow + o4*4);
    float4 v4 = ld4(vrow + o4*4);
    float4 cc = *reinterpret_cast<const float4*>(&c0s[o4*4]);
    float4 w2 = *reinterpret_cast<const float4*>(&W2s[o4*4]);
    float hh[4] = {u4.x+v4.x+cc.x, u4.y+v4.y+cc.y, u4.z+v4.z+cc.z, u4.w+v4.w+cc.w};
    #pragma unroll
    for (int oo = 0; oo < 4; ++oo) {
      int o = o4*4 + oo;
      float acc = hh[oo];
      #pragma unroll
      for (int j4 = 0; j4 < 8; ++j4) {
        float4 a = *reinterpret_cast<const float4*>(&As[o*32 + j4*4]);
        float4 b = *reinterpret_cast<const float4*>(&Bs[o*32 + j4*4]);
        float4 sfv = sf4[j4], hvv = hv4[j4];
        acc = fmaf(a.x,sfv.x, fmaf(a.y,sfv.y, fmaf(a.z,sfv.z, fmaf(a.w,sfv.w, acc))));
        acc = fmaf(b.x,hvv.x, fmaf(b.y,hvv.y, fmaf(b.z,hvv.z, fmaf(b.w,hvv.w, acc))));
      }
      float w2v = (oo==0) ? w2.x : (oo==1) ? w2.y : (oo==2) ? w2.z : w2.w;
      oacc = fmaf(w2v, fmaxf(acc, 0.f), oacc);
    }
  }
  out[e] = oacc;
}

extern "C" void kernel_launch(void* const* d_in, const int* in_sizes, int n_in,
                              void* d_out, int out_size, void* d_ws, size_t ws_size,
                              hipStream_t stream) {
  const int*   src   = (const int*)d_in[0];
  const int*   dst   = (const int*)d_in[1];
  const int*   t     = (const int*)d_in[2];
  const float* msg   = (const float*)d_in[3];
  const float* price = (const float*)d_in[4];
  // d_in[5] trade_t: unused by reference
  const int*   xst   = (const int*)d_in[6];
  const float* memory= (const float*)d_in[7];
  const float* lu    = (const float*)d_in[8];
  const float* w_t   = (const float*)d_in[9];
  const float* b_t   = (const float*)d_in[10];
  const float* W_ih  = (const float*)d_in[11];
  const float* b_ih  = (const float*)d_in[12];
  const float* W_hh  = (const float*)d_in[13];
  const float* b_hh  = (const float*)d_in[14];
  const float* party = (const float*)d_in[15];
  const float* state = (const float*)d_in[16];
  const float* W_sp  = (const float*)d_in[17];
  const float* b_sp  = (const float*)d_in[18];
  const float* W_ihl = (const float*)d_in[19];
  const float* W_hhl = (const float*)d_in[20];
  const float* b_ihl = (const float*)d_in[21];
  const float* b_hhl = (const float*)d_in[22];
  const float* W_pp  = (const float*)d_in[23];
  const float* b_pp  = (const float*)d_in[24];
  const float* W1    = (const float*)d_in[25];
  const float* b1    = (const float*)d_in[26];
  const float* W2    = (const float*)d_in[27];
  const float* b2    = (const float*)d_in[28];
  float* out = (float*)d_out;

  if (ws_size < WS_NEED) {              // loud failure: zero output
    (void)hipMemsetAsync(d_out, 0, (size_t)out_size*4, stream);
    return;
  }

  char* ws = (char*)d_ws;
  u64*   key  = (u64*)(ws + OFF_KEY);
  int*   cnt  = (int*)(ws + OFF_CNT);
  int*   list = (int*)(ws + OFF_LIST);
  float* uv   = (float*)(ws + OFF_UV);
  float* hn   = (float*)(ws + OFF_HN);
  float* A    = (float*)(ws + OFF_A);
  float* B    = (float*)(ws + OFF_B);
  float* c0   = (float*)(ws + OFF_C0);

  (void)hipMemsetAsync(ws, 0, OFF_LIST, stream);   // zero key[] + count
  k_scatter<<<(NE+255)/256, 256, 0, stream>>>(src, dst, t, key);
  k_compact<<<(NN+255)/256, 256, 0, stream>>>(key, list, cnt);
  k_pre<<<17, 256, 0, stream>>>(W1, W_sp, W_pp, b_sp, b_pp, b1, A, B, c0);
  k_lstm<<<(NE+7)/8, 256, 0, stream>>>(price, W_ihl, W_hhl, b_ihl, b_hhl, hn);
  k_gru<<<(NN+63)/64, 512, 0, stream>>>(key, list, cnt, src, dst, t, msg, memory, lu,
                                        w_t, b_t, W_ih, b_ih, W_hh, b_hh, W1, uv);
  k_final<<<(NE+255)/256, 256, 0, stream>>>(src, dst, xst, party, state, uv, hn,
                                            A, B, c0, W2, b2, out);
}